// Round 3
// baseline (765.020 us; speedup 1.0000x reference)
//
#include <hip/hip_runtime.h>
#include <hip/hip_bf16.h>

#define H0 480
#define W0 640
#define H1 240
#define W1 320
#define H2 120
#define W2 160
#define H3 60
#define W3 80

// fp32 weight buffer offsets (in floats) inside d_ws  (transposed pointwise copies)
#define W_PW1T  0      // 5*32  [c*32+o]
#define W_PW2T  160    // 32*64 [c*64+o]
#define W_PW3T  2208   // 64*64 [c*64+o]
#define WBUF_BYTES 65536

// per-batch element counts (fp32)
#define F1_PB (32 * H1 * W1)   // 2,457,600
#define F2_PB (64 * H2 * W2)   // 1,228,800
#define F3_PB (64 * H3 * W3)   //   307,200

// ---------------- K0: transpose pointwise weights (fp32 -> fp32) -------------
__global__ __launch_bounds__(256) void k_cvt(
    const float* __restrict__ pw1, const float* __restrict__ pw2,
    const float* __restrict__ pw3, float* __restrict__ wb)
{
    int t = threadIdx.x;
    for (int i = t; i < 160;  i += 256) { int o = i / 5,  c = i % 5;  wb[W_PW1T + c*32 + o] = pw1[i]; }
    for (int i = t; i < 2048; i += 256) { int o = i >> 5, c = i & 31; wb[W_PW2T + c*64 + o] = pw2[i]; }
    for (int i = t; i < 4096; i += 256) { int o = i >> 6, c = i & 63; wb[W_PW3T + c*64 + o] = pw3[i]; }
}

// ---------------- K1: coords + dwsep1 + ELU -> f1 (chunk-local) --------------
__global__ __launch_bounds__(256) void k_stage1(
    const float* __restrict__ flow, const float* __restrict__ dw1,
    const float* __restrict__ b1, const float* __restrict__ wb,
    float* __restrict__ out, int b0, int nb)
{
    int idx = blockIdx.x * 256 + threadIdx.x;
    if (idx >= nb * H1 * W1) return;
    int ow = idx % W1; int tmp = idx / W1; int oh = tmp % H1; int bl = tmp / H1;
    int b = b0 + bl;
    int ih0 = 2*oh - 1, iw0 = 2*ow - 1;
    // stride-2 pad-1 on even dims: only ih=-1 / iw=-1 can be out of bounds
    float mh[3] = { ih0 >= 0 ? 1.f : 0.f, 1.f, 1.f };
    float mw[3] = { iw0 >= 0 ? 1.f : 0.f, 1.f, 1.f };
    int ihx[3] = { ih0 < 0 ? 0 : ih0, ih0 + 1, ih0 + 2 };
    int iwx[3] = { iw0 < 0 ? 0 : iw0, iw0 + 1, iw0 + 2 };

    float d[5];
    #pragma unroll
    for (int c = 0; c < 2; c++) {
        const float* base = flow + ((size_t)(b*2 + c)) * (H0*W0);
        float acc = 0.f;
        #pragma unroll
        for (int ky = 0; ky < 3; ky++) {
            const float* rp = base + (size_t)ihx[ky] * W0;
            #pragma unroll
            for (int kx = 0; kx < 3; kx++)
                acc = fmaf(dw1[c*9 + ky*3 + kx], (mh[ky]*mw[kx]) * rp[iwx[kx]], acc);
        }
        d[c] = acc;
    }
    { // coordinate channels: x, y, r^2 (zero-padded like the input)
        const float sy = 2.f / (H0 - 1), sx = 2.f / (W0 - 1);
        float accx = 0.f, accy = 0.f, accr = 0.f;
        #pragma unroll
        for (int ky = 0; ky < 3; ky++) {
            float yv = fmaf((float)(ih0 + ky), sy, -1.f);
            #pragma unroll
            for (int kx = 0; kx < 3; kx++) {
                float xv = fmaf((float)(iw0 + kx), sx, -1.f);
                float m = mh[ky] * mw[kx];
                accx = fmaf(dw1[2*9 + ky*3 + kx], m * xv, accx);
                accy = fmaf(dw1[3*9 + ky*3 + kx], m * yv, accy);
                accr = fmaf(dw1[4*9 + ky*3 + kx], m * (xv*xv + yv*yv), accr);
            }
        }
        d[2] = accx; d[3] = accy; d[4] = accr;
    }
    float acc[32];
    #pragma unroll
    for (int o = 0; o < 32; o++) acc[o] = b1[o];
    #pragma unroll
    for (int c = 0; c < 5; c++) {
        float dv = d[c];
        #pragma unroll
        for (int o = 0; o < 32; o++) acc[o] = fmaf(wb[W_PW1T + c*32 + o], dv, acc[o]);
    }
    size_t obase = (size_t)bl * F1_PB + (size_t)oh*W1 + ow;
    #pragma unroll
    for (int o = 0; o < 32; o++) {
        float v = acc[o];
        out[obase + (size_t)o*(H1*W1)] = v > 0.f ? v : (__expf(v) - 1.f);
    }
}

// ---------------- K2: dwsep2 + ELU : f1 -> f2 (chunk-local) ------------------
__global__ __launch_bounds__(256) void k_stage2(
    const float* __restrict__ in, const float* __restrict__ dw2,
    const float* __restrict__ b2, const float* __restrict__ wb,
    float* __restrict__ out, int nb)
{
    int idx = blockIdx.x * 256 + threadIdx.x;
    if (idx >= nb * H2 * W2) return;
    int ow = idx % W2; int tmp = idx / W2; int oh = tmp % H2; int bl = tmp / H2;
    int ih0 = 2*oh - 1, iw0 = 2*ow - 1;
    float mh[3] = { ih0 >= 0 ? 1.f : 0.f, 1.f, 1.f };
    float mw[3] = { iw0 >= 0 ? 1.f : 0.f, 1.f, 1.f };
    int ihx[3] = { ih0 < 0 ? 0 : ih0, ih0 + 1, ih0 + 2 };
    int iwx[3] = { iw0 < 0 ? 0 : iw0, iw0 + 1, iw0 + 2 };
    float m9[9];
    #pragma unroll
    for (int ky = 0; ky < 3; ky++)
        #pragma unroll
        for (int kx = 0; kx < 3; kx++) m9[ky*3 + kx] = mh[ky] * mw[kx];

    float acc[64];
    #pragma unroll
    for (int o = 0; o < 64; o++) acc[o] = b2[o];

    const float* base = in + (size_t)bl * F1_PB;
    for (int c = 0; c < 32; c++) {
        const float* bc = base + (size_t)c * (H1*W1);
        float dv = 0.f;
        #pragma unroll
        for (int ky = 0; ky < 3; ky++) {
            const float* rp = bc + (size_t)ihx[ky] * W1;
            #pragma unroll
            for (int kx = 0; kx < 3; kx++)
                dv = fmaf(dw2[c*9 + ky*3 + kx], m9[ky*3 + kx] * rp[iwx[kx]], dv);
        }
        const float* wrow = wb + W_PW2T + c*64;  // wave-uniform address -> scalar loads
        #pragma unroll
        for (int o = 0; o < 64; o++) acc[o] = fmaf(wrow[o], dv, acc[o]);
    }
    size_t obase = (size_t)bl * F2_PB + (size_t)oh*W2 + ow;
    #pragma unroll
    for (int o = 0; o < 64; o++) {
        float v = acc[o];
        out[obase + (size_t)o*(H2*W2)] = v > 0.f ? v : (__expf(v) - 1.f);
    }
}

// ---------------- K3: dwsep3 + ELU : f2 -> f3 (chunk-local) ------------------
__global__ __launch_bounds__(256) void k_stage3(
    const float* __restrict__ in, const float* __restrict__ dw3,
    const float* __restrict__ b3, const float* __restrict__ wb,
    float* __restrict__ out, int nb)
{
    int idx = blockIdx.x * 256 + threadIdx.x;
    if (idx >= nb * H3 * W3) return;
    int ow = idx % W3; int tmp = idx / W3; int oh = tmp % H3; int bl = tmp / H3;
    int ih0 = 2*oh - 1, iw0 = 2*ow - 1;
    float mh[3] = { ih0 >= 0 ? 1.f : 0.f, 1.f, 1.f };
    float mw[3] = { iw0 >= 0 ? 1.f : 0.f, 1.f, 1.f };
    int ihx[3] = { ih0 < 0 ? 0 : ih0, ih0 + 1, ih0 + 2 };
    int iwx[3] = { iw0 < 0 ? 0 : iw0, iw0 + 1, iw0 + 2 };
    float m9[9];
    #pragma unroll
    for (int ky = 0; ky < 3; ky++)
        #pragma unroll
        for (int kx = 0; kx < 3; kx++) m9[ky*3 + kx] = mh[ky] * mw[kx];

    float acc[64];
    #pragma unroll
    for (int o = 0; o < 64; o++) acc[o] = b3[o];

    const float* base = in + (size_t)bl * F2_PB;
    for (int c = 0; c < 64; c++) {
        const float* bc = base + (size_t)c * (H2*W2);
        float dv = 0.f;
        #pragma unroll
        for (int ky = 0; ky < 3; ky++) {
            const float* rp = bc + (size_t)ihx[ky] * W2;
            #pragma unroll
            for (int kx = 0; kx < 3; kx++)
                dv = fmaf(dw3[c*9 + ky*3 + kx], m9[ky*3 + kx] * rp[iwx[kx]], dv);
        }
        const float* wrow = wb + W_PW3T + c*64;
        #pragma unroll
        for (int o = 0; o < 64; o++) acc[o] = fmaf(wrow[o], dv, acc[o]);
    }
    size_t obase = (size_t)bl * F3_PB + (size_t)oh*W3 + ow;
    #pragma unroll
    for (int o = 0; o < 64; o++) {
        float v = acc[o];
        out[obase + (size_t)o*(H3*W3)] = v > 0.f ? v : (__expf(v) - 1.f);
    }
}

// ---------------- K4: attention pool + MLP + GRU head, one block per batch ---
__global__ __launch_bounds__(256) void k_head(
    const float* __restrict__ f3,
    const float* __restrict__ attn_w, const float* __restrict__ attn_b,
    const float* __restrict__ mlp1_w, const float* __restrict__ mlp1_b,
    const float* __restrict__ mlp2_w, const float* __restrict__ mlp2_b,
    const float* __restrict__ w_ih, const float* __restrict__ b_ih,
    const float* __restrict__ b_hh,
    const float* __restrict__ fc_w, const float* __restrict__ fc_b,
    float* __restrict__ out, int b0)
{
    const int N = H3 * W3;  // 4800
    __shared__ float s_w[H3 * W3];
    __shared__ float s_attn[64];
    __shared__ float s_red[8];
    __shared__ float s_pooled[64];
    __shared__ float s_h1[32];
    __shared__ float s_om[3];
    __shared__ float s_h[32];

    int t = threadIdx.x, bl = blockIdx.x;
    int lane = t & 63, wid = t >> 6;
    if (t < 64) s_attn[t] = attn_w[t];
    __syncthreads();

    const float* fb = f3 + (size_t)bl * F3_PB;
    float ab = attn_b[0];

    // logits
    for (int n = t; n < N; n += 256) {
        float l = ab;
        #pragma unroll 8
        for (int c = 0; c < 64; c++) l = fmaf(s_attn[c], fb[(size_t)c*N + n], l);
        s_w[n] = l;
    }
    __syncthreads();

    // softmax max
    float lmax = -1e30f;
    for (int n = t; n < N; n += 256) lmax = fmaxf(lmax, s_w[n]);
    #pragma unroll
    for (int off = 32; off; off >>= 1) lmax = fmaxf(lmax, __shfl_down(lmax, off, 64));
    if (lane == 0) s_red[wid] = lmax;
    __syncthreads();
    lmax = fmaxf(fmaxf(s_red[0], s_red[1]), fmaxf(s_red[2], s_red[3]));

    // exp + sum (unnormalized weights kept in s_w)
    float lsum = 0.f;
    for (int n = t; n < N; n += 256) { float e = __expf(s_w[n] - lmax); s_w[n] = e; lsum += e; }
    #pragma unroll
    for (int off = 32; off; off >>= 1) lsum += __shfl_down(lsum, off, 64);
    if (lane == 0) s_red[4 + wid] = lsum;
    __syncthreads();
    float invS = 1.f / (s_red[4] + s_red[5] + s_red[6] + s_red[7]);

    // pooled[c] = sum_n f[c,n] * w[n] / S   (one wave per channel slice)
    for (int c = wid; c < 64; c += 4) {
        float s = 0.f;
        for (int n = lane; n < N; n += 64) s = fmaf(fb[(size_t)c*N + n], s_w[n], s);
        #pragma unroll
        for (int off = 32; off; off >>= 1) s += __shfl_down(s, off, 64);
        if (lane == 0) s_pooled[c] = s * invS;
    }
    __syncthreads();

    // mlp1 (64->32) + ELU
    if (t < 32) {
        float a = mlp1_b[t];
        #pragma unroll 8
        for (int c = 0; c < 64; c++) a = fmaf(mlp1_w[t*64 + c], s_pooled[c], a);
        s_h1[t] = a > 0.f ? a : (__expf(a) - 1.f);
    }
    __syncthreads();
    // mlp2 (32->3)
    if (t < 3) {
        float a = mlp2_b[t];
        for (int j = 0; j < 32; j++) a = fmaf(mlp2_w[t*32 + j], s_h1[j], a);
        s_om[t] = a;
    }
    __syncthreads();
    // GRU single step, h0 = 0 (PyTorch gate order r,z,n); gh = b_hh
    if (t < 32) {
        float gr = b_ih[t], gz = b_ih[32 + t], gn = b_ih[64 + t];
        #pragma unroll
        for (int k = 0; k < 3; k++) {
            float ok = s_om[k];
            gr = fmaf(w_ih[t*3 + k],        ok, gr);
            gz = fmaf(w_ih[(32 + t)*3 + k], ok, gz);
            gn = fmaf(w_ih[(64 + t)*3 + k], ok, gn);
        }
        float hr = b_hh[t], hz = b_hh[32 + t], hn = b_hh[64 + t];
        float r = 1.f / (1.f + __expf(-(gr + hr)));
        float z = 1.f / (1.f + __expf(-(gz + hz)));
        float nn = tanhf(gn + r * hn);
        s_h[t] = (1.f - z) * nn;   // + z*h0 with h0=0
    }
    __syncthreads();
    if (t < 3) {
        float dl = fc_b[t];
        for (int j = 0; j < 32; j++) dl = fmaf(fc_w[t*32 + j], s_h[j], dl);
        out[(b0 + bl)*3 + t] = s_om[t] + dl;
    }
}

// ---------------- host ----------------
extern "C" void kernel_launch(void* const* d_in, const int* in_sizes, int n_in,
                              void* d_out, int out_size, void* d_ws, size_t ws_size,
                              hipStream_t stream)
{
    const float* flow = (const float*)d_in[0];
    float* wb = (float*)d_ws;

    // pick largest batch-chunk C whose scratch fits (cap 16 so f1 chunk < L3)
    // per-batch bytes: (F1_PB + F2_PB + F3_PB) * 4 = 15,974,400
    const size_t PB = ((size_t)F1_PB + F2_PB + F3_PB) * 4;
    int C = 1;
    for (int c = 16; c >= 1; c >>= 1) {
        if ((size_t)WBUF_BYTES + (size_t)c * PB <= ws_size) { C = c; break; }
    }

    float* f1 = (float*)((char*)d_ws + WBUF_BYTES);
    float* f2 = f1 + (size_t)C * F1_PB;
    float* f3 = f2 + (size_t)C * F2_PB;

    k_cvt<<<1, 256, 0, stream>>>(
        (const float*)d_in[2], (const float*)d_in[5], (const float*)d_in[8], wb);

    for (int b0 = 0; b0 < 32; b0 += C) {
        int nb = (32 - b0) < C ? (32 - b0) : C;
        k_stage1<<<(nb*H1*W1 + 255)/256, 256, 0, stream>>>(
            flow, (const float*)d_in[1], (const float*)d_in[3], wb, f1, b0, nb);
        k_stage2<<<(nb*H2*W2 + 255)/256, 256, 0, stream>>>(
            f1, (const float*)d_in[4], (const float*)d_in[6], wb, f2, nb);
        k_stage3<<<(nb*H3*W3 + 255)/256, 256, 0, stream>>>(
            f2, (const float*)d_in[7], (const float*)d_in[9], wb, f3, nb);
        k_head<<<nb, 256, 0, stream>>>(f3,
            (const float*)d_in[10], (const float*)d_in[11],
            (const float*)d_in[12], (const float*)d_in[13],
            (const float*)d_in[14], (const float*)d_in[15],
            (const float*)d_in[16], (const float*)d_in[18],
            (const float*)d_in[19], (const float*)d_in[20],
            (const float*)d_in[21], (float*)d_out, b0);
    }
}

// Round 4
// 455.536 us; speedup vs baseline: 1.6794x; 1.6794x over previous
//
#include <hip/hip_runtime.h>
#include <hip/hip_bf16.h>

#define H0 480
#define W0 640
#define H1 240
#define W1 320
#define H2 120
#define W2 160
#define H3 60
#define W3 80

// fp32 weight buffer offsets (in floats) inside d_ws  (transposed pointwise copies)
#define W_PW1T  0      // 5*32  [c*32+o]
#define W_PW2T  160    // 32*64 [c*64+o]
#define W_PW3T  2208   // 64*64 [c*64+o]
#define WBUF_BYTES 65536

// per-batch element counts (fp32)
#define F1_PB (32 * H1 * W1)   // 2,457,600
#define F2_PB (64 * H2 * W2)   // 1,228,800
#define F3_PB (64 * H3 * W3)   //   307,200

// ---------------- K0: transpose pointwise weights (fp32 -> fp32) -------------
__global__ __launch_bounds__(256) void k_cvt(
    const float* __restrict__ pw1, const float* __restrict__ pw2,
    const float* __restrict__ pw3, float* __restrict__ wb)
{
    int t = threadIdx.x;
    for (int i = t; i < 160;  i += 256) { int o = i / 5,  c = i % 5;  wb[W_PW1T + c*32 + o] = pw1[i]; }
    for (int i = t; i < 2048; i += 256) { int o = i >> 5, c = i & 31; wb[W_PW2T + c*64 + o] = pw2[i]; }
    for (int i = t; i < 4096; i += 256) { int o = i >> 6, c = i & 63; wb[W_PW3T + c*64 + o] = pw3[i]; }
}

// ---------------- K1: coords + dwsep1 + ELU -> f1 (chunk-local) --------------
__global__ __launch_bounds__(256) void k_stage1(
    const float* __restrict__ flow, const float* __restrict__ dw1,
    const float* __restrict__ b1, const float* __restrict__ wb,
    float* __restrict__ out, int b0, int nb)
{
    int idx = blockIdx.x * 256 + threadIdx.x;
    if (idx >= nb * H1 * W1) return;
    int ow = idx % W1; int tmp = idx / W1; int oh = tmp % H1; int bl = tmp / H1;
    int b = b0 + bl;
    int ih0 = 2*oh - 1, iw0 = 2*ow - 1;
    // stride-2 pad-1 on even dims: only ih=-1 / iw=-1 can be out of bounds
    float mh[3] = { ih0 >= 0 ? 1.f : 0.f, 1.f, 1.f };
    float mw[3] = { iw0 >= 0 ? 1.f : 0.f, 1.f, 1.f };
    int ihx[3] = { ih0 < 0 ? 0 : ih0, ih0 + 1, ih0 + 2 };
    int iwx[3] = { iw0 < 0 ? 0 : iw0, iw0 + 1, iw0 + 2 };

    float d[5];
    #pragma unroll
    for (int c = 0; c < 2; c++) {
        const float* base = flow + ((size_t)(b*2 + c)) * (H0*W0);
        float acc = 0.f;
        #pragma unroll
        for (int ky = 0; ky < 3; ky++) {
            const float* rp = base + (size_t)ihx[ky] * W0;
            #pragma unroll
            for (int kx = 0; kx < 3; kx++)
                acc = fmaf(dw1[c*9 + ky*3 + kx], (mh[ky]*mw[kx]) * rp[iwx[kx]], acc);
        }
        d[c] = acc;
    }
    { // coordinate channels: x, y, r^2 (zero-padded like the input)
        const float sy = 2.f / (H0 - 1), sx = 2.f / (W0 - 1);
        float accx = 0.f, accy = 0.f, accr = 0.f;
        #pragma unroll
        for (int ky = 0; ky < 3; ky++) {
            float yv = fmaf((float)(ih0 + ky), sy, -1.f);
            #pragma unroll
            for (int kx = 0; kx < 3; kx++) {
                float xv = fmaf((float)(iw0 + kx), sx, -1.f);
                float m = mh[ky] * mw[kx];
                accx = fmaf(dw1[2*9 + ky*3 + kx], m * xv, accx);
                accy = fmaf(dw1[3*9 + ky*3 + kx], m * yv, accy);
                accr = fmaf(dw1[4*9 + ky*3 + kx], m * (xv*xv + yv*yv), accr);
            }
        }
        d[2] = accx; d[3] = accy; d[4] = accr;
    }
    float acc[32];
    #pragma unroll
    for (int o = 0; o < 32; o++) acc[o] = b1[o];
    #pragma unroll
    for (int c = 0; c < 5; c++) {
        float dv = d[c];
        #pragma unroll
        for (int o = 0; o < 32; o++) acc[o] = fmaf(wb[W_PW1T + c*32 + o], dv, acc[o]);
    }
    size_t obase = (size_t)bl * F1_PB + (size_t)oh*W1 + ow;
    #pragma unroll
    for (int o = 0; o < 32; o++) {
        float v = acc[o];
        out[obase + (size_t)o*(H1*W1)] = v > 0.f ? v : (__expf(v) - 1.f);
    }
}

// ---------------- K2: dwsep2 + ELU : f1 -> f2 (chunk-local) ------------------
__global__ __launch_bounds__(256) void k_stage2(
    const float* __restrict__ in, const float* __restrict__ dw2,
    const float* __restrict__ b2, const float* __restrict__ wb,
    float* __restrict__ out, int nb)
{
    int idx = blockIdx.x * 256 + threadIdx.x;
    if (idx >= nb * H2 * W2) return;
    int ow = idx % W2; int tmp = idx / W2; int oh = tmp % H2; int bl = tmp / H2;
    int ih0 = 2*oh - 1, iw0 = 2*ow - 1;
    float mh[3] = { ih0 >= 0 ? 1.f : 0.f, 1.f, 1.f };
    float mw[3] = { iw0 >= 0 ? 1.f : 0.f, 1.f, 1.f };
    int ihx[3] = { ih0 < 0 ? 0 : ih0, ih0 + 1, ih0 + 2 };
    int iwx[3] = { iw0 < 0 ? 0 : iw0, iw0 + 1, iw0 + 2 };
    float m9[9];
    #pragma unroll
    for (int ky = 0; ky < 3; ky++)
        #pragma unroll
        for (int kx = 0; kx < 3; kx++) m9[ky*3 + kx] = mh[ky] * mw[kx];

    float acc[64];
    #pragma unroll
    for (int o = 0; o < 64; o++) acc[o] = b2[o];

    const float* base = in + (size_t)bl * F1_PB;
    for (int c = 0; c < 32; c++) {
        const float* bc = base + (size_t)c * (H1*W1);
        float dv = 0.f;
        #pragma unroll
        for (int ky = 0; ky < 3; ky++) {
            const float* rp = bc + (size_t)ihx[ky] * W1;
            #pragma unroll
            for (int kx = 0; kx < 3; kx++)
                dv = fmaf(dw2[c*9 + ky*3 + kx], m9[ky*3 + kx] * rp[iwx[kx]], dv);
        }
        const float* wrow = wb + W_PW2T + c*64;  // wave-uniform address -> scalar loads
        #pragma unroll
        for (int o = 0; o < 64; o++) acc[o] = fmaf(wrow[o], dv, acc[o]);
    }
    size_t obase = (size_t)bl * F2_PB + (size_t)oh*W2 + ow;
    #pragma unroll
    for (int o = 0; o < 64; o++) {
        float v = acc[o];
        out[obase + (size_t)o*(H2*W2)] = v > 0.f ? v : (__expf(v) - 1.f);
    }
}

// ---------------- K3: dwsep3 + ELU : f2 -> f3 (chunk slice of full buffer) ---
__global__ __launch_bounds__(256) void k_stage3(
    const float* __restrict__ in, const float* __restrict__ dw3,
    const float* __restrict__ b3, const float* __restrict__ wb,
    float* __restrict__ out, int nb)
{
    int idx = blockIdx.x * 256 + threadIdx.x;
    if (idx >= nb * H3 * W3) return;
    int ow = idx % W3; int tmp = idx / W3; int oh = tmp % H3; int bl = tmp / H3;
    int ih0 = 2*oh - 1, iw0 = 2*ow - 1;
    float mh[3] = { ih0 >= 0 ? 1.f : 0.f, 1.f, 1.f };
    float mw[3] = { iw0 >= 0 ? 1.f : 0.f, 1.f, 1.f };
    int ihx[3] = { ih0 < 0 ? 0 : ih0, ih0 + 1, ih0 + 2 };
    int iwx[3] = { iw0 < 0 ? 0 : iw0, iw0 + 1, iw0 + 2 };
    float m9[9];
    #pragma unroll
    for (int ky = 0; ky < 3; ky++)
        #pragma unroll
        for (int kx = 0; kx < 3; kx++) m9[ky*3 + kx] = mh[ky] * mw[kx];

    float acc[64];
    #pragma unroll
    for (int o = 0; o < 64; o++) acc[o] = b3[o];

    const float* base = in + (size_t)bl * F2_PB;
    for (int c = 0; c < 64; c++) {
        const float* bc = base + (size_t)c * (H2*W2);
        float dv = 0.f;
        #pragma unroll
        for (int ky = 0; ky < 3; ky++) {
            const float* rp = bc + (size_t)ihx[ky] * W2;
            #pragma unroll
            for (int kx = 0; kx < 3; kx++)
                dv = fmaf(dw3[c*9 + ky*3 + kx], m9[ky*3 + kx] * rp[iwx[kx]], dv);
        }
        const float* wrow = wb + W_PW3T + c*64;
        #pragma unroll
        for (int o = 0; o < 64; o++) acc[o] = fmaf(wrow[o], dv, acc[o]);
    }
    size_t obase = (size_t)bl * F3_PB + (size_t)oh*W3 + ow;
    #pragma unroll
    for (int o = 0; o < 64; o++) {
        float v = acc[o];
        out[obase + (size_t)o*(H3*W3)] = v > 0.f ? v : (__expf(v) - 1.f);
    }
}

// ---------------- K4: attention pool + MLP + GRU head -----------------------
// one block (1024 threads, 16 waves) per batch, all 32 batches in one launch
__global__ __launch_bounds__(1024) void k_head(
    const float* __restrict__ f3,
    const float* __restrict__ attn_w, const float* __restrict__ attn_b,
    const float* __restrict__ mlp1_w, const float* __restrict__ mlp1_b,
    const float* __restrict__ mlp2_w, const float* __restrict__ mlp2_b,
    const float* __restrict__ w_ih, const float* __restrict__ b_ih,
    const float* __restrict__ b_hh,
    const float* __restrict__ fc_w, const float* __restrict__ fc_b,
    float* __restrict__ out)
{
    const int N  = H3 * W3;   // 4800
    const int N4 = N / 4;     // 1200
    __shared__ float s_w[H3 * W3];
    __shared__ float s_attn[64];
    __shared__ float s_redm[16];
    __shared__ float s_reds[16];
    __shared__ float s_inv[1];
    __shared__ float s_pooled[64];
    __shared__ float s_h1[32];
    __shared__ float s_om[3];
    __shared__ float s_h[32];

    int t = threadIdx.x, b = blockIdx.x;
    int lane = t & 63, wid = t >> 6;   // 16 waves
    if (t < 64) s_attn[t] = attn_w[t];
    __syncthreads();

    const float4* fb4 = (const float4*)(f3 + (size_t)b * F3_PB);
    float ab = attn_b[0];

    // ---- logits (float4 over n) + fused local max ----
    float lmax = -1e30f;
    for (int n4 = t; n4 < N4; n4 += 1024) {
        float4 l = make_float4(ab, ab, ab, ab);
        #pragma unroll 8
        for (int c = 0; c < 64; c++) {
            float4 v = fb4[c * N4 + n4];
            float a = s_attn[c];
            l.x = fmaf(a, v.x, l.x); l.y = fmaf(a, v.y, l.y);
            l.z = fmaf(a, v.z, l.z); l.w = fmaf(a, v.w, l.w);
        }
        ((float4*)s_w)[n4] = l;
        lmax = fmaxf(lmax, fmaxf(fmaxf(l.x, l.y), fmaxf(l.z, l.w)));
    }
    #pragma unroll
    for (int off = 32; off; off >>= 1) lmax = fmaxf(lmax, __shfl_down(lmax, off, 64));
    if (lane == 0) s_redm[wid] = lmax;
    __syncthreads();
    {
        float m = s_redm[0];
        #pragma unroll
        for (int i = 1; i < 16; i++) m = fmaxf(m, s_redm[i]);
        lmax = m;
    }

    // ---- exp + sum (unnormalized weights kept in s_w) ----
    float lsum = 0.f;
    for (int n = t; n < N; n += 1024) { float e = __expf(s_w[n] - lmax); s_w[n] = e; lsum += e; }
    #pragma unroll
    for (int off = 32; off; off >>= 1) lsum += __shfl_down(lsum, off, 64);
    if (lane == 0) s_reds[wid] = lsum;
    __syncthreads();
    if (t == 0) {
        float s = 0.f;
        #pragma unroll
        for (int i = 0; i < 16; i++) s += s_reds[i];
        s_inv[0] = 1.f / s;
    }
    __syncthreads();
    float invS = s_inv[0];

    // ---- pooled[c] = sum_n f[c,n] w[n] / S  (one wave per channel, float4) ----
    const float4* sw4 = (const float4*)s_w;
    for (int c = wid; c < 64; c += 16) {
        float s = 0.f;
        for (int i = lane; i < N4; i += 64) {
            float4 v = fb4[c * N4 + i];
            float4 w = sw4[i];
            s = fmaf(v.x, w.x, s); s = fmaf(v.y, w.y, s);
            s = fmaf(v.z, w.z, s); s = fmaf(v.w, w.w, s);
        }
        #pragma unroll
        for (int off = 32; off; off >>= 1) s += __shfl_down(s, off, 64);
        if (lane == 0) s_pooled[c] = s * invS;
    }
    __syncthreads();

    // ---- mlp1 (64->32) + ELU ----
    if (t < 32) {
        float a = mlp1_b[t];
        #pragma unroll 8
        for (int c = 0; c < 64; c++) a = fmaf(mlp1_w[t*64 + c], s_pooled[c], a);
        s_h1[t] = a > 0.f ? a : (__expf(a) - 1.f);
    }
    __syncthreads();
    // ---- mlp2 (32->3) ----
    if (t < 3) {
        float a = mlp2_b[t];
        for (int j = 0; j < 32; j++) a = fmaf(mlp2_w[t*32 + j], s_h1[j], a);
        s_om[t] = a;
    }
    __syncthreads();
    // ---- GRU single step, h0 = 0 (PyTorch gate order r,z,n); gh = b_hh ----
    if (t < 32) {
        float gr = b_ih[t], gz = b_ih[32 + t], gn = b_ih[64 + t];
        #pragma unroll
        for (int k = 0; k < 3; k++) {
            float ok = s_om[k];
            gr = fmaf(w_ih[t*3 + k],        ok, gr);
            gz = fmaf(w_ih[(32 + t)*3 + k], ok, gz);
            gn = fmaf(w_ih[(64 + t)*3 + k], ok, gn);
        }
        float hr = b_hh[t], hz = b_hh[32 + t], hn = b_hh[64 + t];
        float r = 1.f / (1.f + __expf(-(gr + hr)));
        float z = 1.f / (1.f + __expf(-(gz + hz)));
        float nn = tanhf(gn + r * hn);
        s_h[t] = (1.f - z) * nn;   // + z*h0 with h0=0
    }
    __syncthreads();
    if (t < 3) {
        float dl = fc_b[t];
        for (int j = 0; j < 32; j++) dl = fmaf(fc_w[t*32 + j], s_h[j], dl);
        out[b*3 + t] = s_om[t] + dl;
    }
}

// ---------------- host ----------------
extern "C" void kernel_launch(void* const* d_in, const int* in_sizes, int n_in,
                              void* d_out, int out_size, void* d_ws, size_t ws_size,
                              hipStream_t stream)
{
    const float* flow = (const float*)d_in[0];
    float* wb = (float*)d_ws;

    // layout: [wbuf][f3 all 32 batches][f1 chunk][f2 chunk]
    const size_t F3_ALL_BYTES = (size_t)32 * F3_PB * 4;   // 39.3 MB
    size_t avail = (ws_size > WBUF_BYTES + F3_ALL_BYTES)
                 ? ws_size - WBUF_BYTES - F3_ALL_BYTES : 0;
    const size_t PB12 = ((size_t)F1_PB + F2_PB) * 4;      // 14.75 MB per batch
    int C = 1;
    for (int c = 32; c >= 1; c >>= 1) {
        if ((size_t)c * PB12 <= avail) { C = c; break; }
    }

    float* f3 = (float*)((char*)d_ws + WBUF_BYTES);
    float* f1 = f3 + (size_t)32 * F3_PB;
    float* f2 = f1 + (size_t)C * F1_PB;

    k_cvt<<<1, 256, 0, stream>>>(
        (const float*)d_in[2], (const float*)d_in[5], (const float*)d_in[8], wb);

    for (int b0 = 0; b0 < 32; b0 += C) {
        int nb = (32 - b0) < C ? (32 - b0) : C;
        k_stage1<<<(nb*H1*W1 + 255)/256, 256, 0, stream>>>(
            flow, (const float*)d_in[1], (const float*)d_in[3], wb, f1, b0, nb);
        k_stage2<<<(nb*H2*W2 + 255)/256, 256, 0, stream>>>(
            f1, (const float*)d_in[4], (const float*)d_in[6], wb, f2, nb);
        k_stage3<<<(nb*H3*W3 + 255)/256, 256, 0, stream>>>(
            f2, (const float*)d_in[7], (const float*)d_in[9], wb, f3 + (size_t)b0 * F3_PB, nb);
    }

    k_head<<<32, 1024, 0, stream>>>(f3,
        (const float*)d_in[10], (const float*)d_in[11],
        (const float*)d_in[12], (const float*)d_in[13],
        (const float*)d_in[14], (const float*)d_in[15],
        (const float*)d_in[16], (const float*)d_in[18],
        (const float*)d_in[19], (const float*)d_in[20],
        (const float*)d_in[21], (float*)d_out);
}

// Round 5
// 436.030 us; speedup vs baseline: 1.7545x; 1.0447x over previous
//
#include <hip/hip_runtime.h>
#include <hip/hip_bf16.h>

#define H0 480
#define W0 640
#define H1 240
#define W1 320
#define H2 120
#define W2 160
#define H3 60
#define W3 80

// fp32 weight buffer offsets (in floats) inside d_ws  (transposed pointwise copies)
#define W_PW1T  0      // 5*32  [c*32+o]
#define W_PW2T  160    // 32*64 [c*64+o]
#define W_PW3T  2208   // 64*64 [c*64+o]
#define WBUF_BYTES 65536

// per-batch element counts (fp32)
#define F1_PB (32 * H1 * W1)   // 2,457,600
#define F2_PB (64 * H2 * W2)   // 1,228,800
#define F3_PB (64 * H3 * W3)   //   307,200

// fused stage1+2 tile
#define TH 4
#define TW 16
#define LR (2*TH + 1)   // 9  f1 rows in tile
#define LC (2*TW + 1)   // 33 f1 cols in tile
#define LN (LR * LC)    // 297 f1 pixels in tile

// ---------------- K0: transpose pointwise weights (fp32 -> fp32) -------------
__global__ __launch_bounds__(256) void k_cvt(
    const float* __restrict__ pw1, const float* __restrict__ pw2,
    const float* __restrict__ pw3, float* __restrict__ wb)
{
    int t = threadIdx.x;
    for (int i = t; i < 160;  i += 256) { int o = i / 5,  c = i % 5;  wb[W_PW1T + c*32 + o] = pw1[i]; }
    for (int i = t; i < 2048; i += 256) { int o = i >> 5, c = i & 31; wb[W_PW2T + c*64 + o] = pw2[i]; }
    for (int i = t; i < 4096; i += 256) { int o = i >> 6, c = i & 63; wb[W_PW3T + c*64 + o] = pw3[i]; }
}

// ---------------- K12: fused (coords + dwsep1 + ELU) -> LDS -> (dwsep2 + ELU) -> f2
// grid (300 tiles, 32 batches), 128 threads. Tile = 4x16 f2 pixels.
// Step A: 9x33 f1 tile (32 ch, post-ELU, zero-padded halo) into LDS.
// Step B: 64 px x 2 channel-halves; dw2 from LDS, pw2 via wave-uniform s-loads.
__global__ __launch_bounds__(128) void k_fuse12(
    const float* __restrict__ flow, const float* __restrict__ dw1,
    const float* __restrict__ b1, const float* __restrict__ dw2,
    const float* __restrict__ b2, const float* __restrict__ wb,
    float* __restrict__ out)
{
    __shared__ float s_f1[32 * LN];   // 38,016 B

    int t = threadIdx.x;
    int tile = blockIdx.x;            // 0..299
    int b = blockIdx.y;
    int tx = tile % 10, ty = tile / 10;        // tx: 0..9 (W), ty: 0..29 (H)
    int th0 = ty * TH, tw0 = tx * TW;          // f2 tile origin

    // ---- step A: compute f1 tile into LDS ----
    for (int li = t; li < LN; li += 128) {
        int lh = li / LC, lw = li % LC;
        int h1 = 2*th0 - 1 + lh;               // [-1, 239]
        int w1 = 2*tw0 - 1 + lw;               // [-1, 319]
        if (h1 < 0 || w1 < 0) {                // zero-pad halo (upper edges in range)
            #pragma unroll
            for (int c = 0; c < 32; c++) s_f1[c*LN + li] = 0.f;
            continue;
        }
        int ih0 = 2*h1 - 1, iw0 = 2*w1 - 1;
        float mh[3] = { ih0 >= 0 ? 1.f : 0.f, 1.f, 1.f };
        float mw[3] = { iw0 >= 0 ? 1.f : 0.f, 1.f, 1.f };
        int ihx[3] = { ih0 < 0 ? 0 : ih0, ih0 + 1, ih0 + 2 };
        int iwx[3] = { iw0 < 0 ? 0 : iw0, iw0 + 1, iw0 + 2 };

        float d[5];
        #pragma unroll
        for (int c = 0; c < 2; c++) {
            const float* base = flow + ((size_t)(b*2 + c)) * (H0*W0);
            float acc = 0.f;
            #pragma unroll
            for (int ky = 0; ky < 3; ky++) {
                const float* rp = base + (size_t)ihx[ky] * W0;
                #pragma unroll
                for (int kx = 0; kx < 3; kx++)
                    acc = fmaf(dw1[c*9 + ky*3 + kx], (mh[ky]*mw[kx]) * rp[iwx[kx]], acc);
            }
            d[c] = acc;
        }
        {   // coordinate channels x, y, r^2 (zero-padded like the input)
            const float sy = 2.f / (H0 - 1), sx = 2.f / (W0 - 1);
            float accx = 0.f, accy = 0.f, accr = 0.f;
            #pragma unroll
            for (int ky = 0; ky < 3; ky++) {
                float yv = fmaf((float)(ih0 + ky), sy, -1.f);
                #pragma unroll
                for (int kx = 0; kx < 3; kx++) {
                    float xv = fmaf((float)(iw0 + kx), sx, -1.f);
                    float m = mh[ky] * mw[kx];
                    accx = fmaf(dw1[2*9 + ky*3 + kx], m * xv, accx);
                    accy = fmaf(dw1[3*9 + ky*3 + kx], m * yv, accy);
                    accr = fmaf(dw1[4*9 + ky*3 + kx], m * (xv*xv + yv*yv), accr);
                }
            }
            d[2] = accx; d[3] = accy; d[4] = accr;
        }
        float acc[32];
        #pragma unroll
        for (int o = 0; o < 32; o++) acc[o] = b1[o];
        #pragma unroll
        for (int c = 0; c < 5; c++) {
            float dv = d[c];
            #pragma unroll
            for (int o = 0; o < 32; o++) acc[o] = fmaf(wb[W_PW1T + c*32 + o], dv, acc[o]);
        }
        #pragma unroll
        for (int o = 0; o < 32; o++) {
            float v = acc[o];
            s_f1[o*LN + li] = v > 0.f ? v : (__expf(v) - 1.f);
        }
    }
    __syncthreads();

    // ---- step B: dwsep2 from LDS ----
    int p    = t & 63;        // 64 pixels
    int half = t >> 6;        // wave-uniform channel half
    int lh2 = p >> 4, lw2 = p & 15;
    int oh2 = th0 + lh2, ow2 = tw0 + lw2;

    float acc[32];
    #pragma unroll
    for (int o = 0; o < 32; o++) acc[o] = b2[half*32 + o];

    int lbase = 2*lh2*LC + 2*lw2;
    for (int c = 0; c < 32; c++) {
        const float* w9 = dw2 + c*9;               // wave-uniform -> s_load
        const float* sf = s_f1 + c*LN + lbase;
        float dv = 0.f;
        #pragma unroll
        for (int ky = 0; ky < 3; ky++) {
            const float* r = sf + ky*LC;
            dv = fmaf(w9[ky*3 + 0], r[0], dv);
            dv = fmaf(w9[ky*3 + 1], r[1], dv);
            dv = fmaf(w9[ky*3 + 2], r[2], dv);
        }
        const float* wrow = wb + W_PW2T + c*64 + half*32;   // wave-uniform -> s_load
        #pragma unroll
        for (int o = 0; o < 32; o++) acc[o] = fmaf(wrow[o], dv, acc[o]);
    }
    size_t obase = ((size_t)b*64 + half*32) * (H2*W2) + (size_t)oh2*W2 + ow2;
    #pragma unroll
    for (int o = 0; o < 32; o++) {
        float v = acc[o];
        out[obase + (size_t)o*(H2*W2)] = v > 0.f ? v : (__expf(v) - 1.f);
    }
}

// ---------------- K3: dwsep3 + ELU : f2 -> f3 (full batch) -------------------
__global__ __launch_bounds__(256) void k_stage3(
    const float* __restrict__ in, const float* __restrict__ dw3,
    const float* __restrict__ b3, const float* __restrict__ wb,
    float* __restrict__ out, int nb)
{
    int idx = blockIdx.x * 256 + threadIdx.x;
    if (idx >= nb * H3 * W3) return;
    int ow = idx % W3; int tmp = idx / W3; int oh = tmp % H3; int bl = tmp / H3;
    int ih0 = 2*oh - 1, iw0 = 2*ow - 1;
    float mh[3] = { ih0 >= 0 ? 1.f : 0.f, 1.f, 1.f };
    float mw[3] = { iw0 >= 0 ? 1.f : 0.f, 1.f, 1.f };
    int ihx[3] = { ih0 < 0 ? 0 : ih0, ih0 + 1, ih0 + 2 };
    int iwx[3] = { iw0 < 0 ? 0 : iw0, iw0 + 1, iw0 + 2 };
    float m9[9];
    #pragma unroll
    for (int ky = 0; ky < 3; ky++)
        #pragma unroll
        for (int kx = 0; kx < 3; kx++) m9[ky*3 + kx] = mh[ky] * mw[kx];

    float acc[64];
    #pragma unroll
    for (int o = 0; o < 64; o++) acc[o] = b3[o];

    const float* base = in + (size_t)bl * F2_PB;
    for (int c = 0; c < 64; c++) {
        const float* bc = base + (size_t)c * (H2*W2);
        float dv = 0.f;
        #pragma unroll
        for (int ky = 0; ky < 3; ky++) {
            const float* rp = bc + (size_t)ihx[ky] * W2;
            #pragma unroll
            for (int kx = 0; kx < 3; kx++)
                dv = fmaf(dw3[c*9 + ky*3 + kx], m9[ky*3 + kx] * rp[iwx[kx]], dv);
        }
        const float* wrow = wb + W_PW3T + c*64;
        #pragma unroll
        for (int o = 0; o < 64; o++) acc[o] = fmaf(wrow[o], dv, acc[o]);
    }
    size_t obase = (size_t)bl * F3_PB + (size_t)oh*W3 + ow;
    #pragma unroll
    for (int o = 0; o < 64; o++) {
        float v = acc[o];
        out[obase + (size_t)o*(H3*W3)] = v > 0.f ? v : (__expf(v) - 1.f);
    }
}

// ---------------- K4: attention pool + MLP + GRU head -----------------------
// one block (1024 threads, 16 waves) per batch, all 32 batches in one launch
__global__ __launch_bounds__(1024) void k_head(
    const float* __restrict__ f3,
    const float* __restrict__ attn_w, const float* __restrict__ attn_b,
    const float* __restrict__ mlp1_w, const float* __restrict__ mlp1_b,
    const float* __restrict__ mlp2_w, const float* __restrict__ mlp2_b,
    const float* __restrict__ w_ih, const float* __restrict__ b_ih,
    const float* __restrict__ b_hh,
    const float* __restrict__ fc_w, const float* __restrict__ fc_b,
    float* __restrict__ out)
{
    const int N  = H3 * W3;   // 4800
    const int N4 = N / 4;     // 1200
    __shared__ float s_w[H3 * W3];
    __shared__ float s_attn[64];
    __shared__ float s_redm[16];
    __shared__ float s_reds[16];
    __shared__ float s_inv[1];
    __shared__ float s_pooled[64];
    __shared__ float s_h1[32];
    __shared__ float s_om[3];
    __shared__ float s_h[32];

    int t = threadIdx.x, b = blockIdx.x;
    int lane = t & 63, wid = t >> 6;   // 16 waves
    if (t < 64) s_attn[t] = attn_w[t];
    __syncthreads();

    const float4* fb4 = (const float4*)(f3 + (size_t)b * F3_PB);
    float ab = attn_b[0];

    // ---- logits (float4 over n) + fused local max ----
    float lmax = -1e30f;
    for (int n4 = t; n4 < N4; n4 += 1024) {
        float4 l = make_float4(ab, ab, ab, ab);
        #pragma unroll 8
        for (int c = 0; c < 64; c++) {
            float4 v = fb4[c * N4 + n4];
            float a = s_attn[c];
            l.x = fmaf(a, v.x, l.x); l.y = fmaf(a, v.y, l.y);
            l.z = fmaf(a, v.z, l.z); l.w = fmaf(a, v.w, l.w);
        }
        ((float4*)s_w)[n4] = l;
        lmax = fmaxf(lmax, fmaxf(fmaxf(l.x, l.y), fmaxf(l.z, l.w)));
    }
    #pragma unroll
    for (int off = 32; off; off >>= 1) lmax = fmaxf(lmax, __shfl_down(lmax, off, 64));
    if (lane == 0) s_redm[wid] = lmax;
    __syncthreads();
    {
        float m = s_redm[0];
        #pragma unroll
        for (int i = 1; i < 16; i++) m = fmaxf(m, s_redm[i]);
        lmax = m;
    }

    // ---- exp + sum (unnormalized weights kept in s_w) ----
    float lsum = 0.f;
    for (int n = t; n < N; n += 1024) { float e = __expf(s_w[n] - lmax); s_w[n] = e; lsum += e; }
    #pragma unroll
    for (int off = 32; off; off >>= 1) lsum += __shfl_down(lsum, off, 64);
    if (lane == 0) s_reds[wid] = lsum;
    __syncthreads();
    if (t == 0) {
        float s = 0.f;
        #pragma unroll
        for (int i = 0; i < 16; i++) s += s_reds[i];
        s_inv[0] = 1.f / s;
    }
    __syncthreads();
    float invS = s_inv[0];

    // ---- pooled[c] = sum_n f[c,n] w[n] / S  (one wave per channel, float4) ----
    const float4* sw4 = (const float4*)s_w;
    for (int c = wid; c < 64; c += 16) {
        float s = 0.f;
        for (int i = lane; i < N4; i += 64) {
            float4 v = fb4[c * N4 + i];
            float4 w = sw4[i];
            s = fmaf(v.x, w.x, s); s = fmaf(v.y, w.y, s);
            s = fmaf(v.z, w.z, s); s = fmaf(v.w, w.w, s);
        }
        #pragma unroll
        for (int off = 32; off; off >>= 1) s += __shfl_down(s, off, 64);
        if (lane == 0) s_pooled[c] = s * invS;
    }
    __syncthreads();

    // ---- mlp1 (64->32) + ELU ----
    if (t < 32) {
        float a = mlp1_b[t];
        #pragma unroll 8
        for (int c = 0; c < 64; c++) a = fmaf(mlp1_w[t*64 + c], s_pooled[c], a);
        s_h1[t] = a > 0.f ? a : (__expf(a) - 1.f);
    }
    __syncthreads();
    // ---- mlp2 (32->3) ----
    if (t < 3) {
        float a = mlp2_b[t];
        for (int j = 0; j < 32; j++) a = fmaf(mlp2_w[t*32 + j], s_h1[j], a);
        s_om[t] = a;
    }
    __syncthreads();
    // ---- GRU single step, h0 = 0 (PyTorch gate order r,z,n); gh = b_hh ----
    if (t < 32) {
        float gr = b_ih[t], gz = b_ih[32 + t], gn = b_ih[64 + t];
        #pragma unroll
        for (int k = 0; k < 3; k++) {
            float ok = s_om[k];
            gr = fmaf(w_ih[t*3 + k],        ok, gr);
            gz = fmaf(w_ih[(32 + t)*3 + k], ok, gz);
            gn = fmaf(w_ih[(64 + t)*3 + k], ok, gn);
        }
        float hr = b_hh[t], hz = b_hh[32 + t], hn = b_hh[64 + t];
        float r = 1.f / (1.f + __expf(-(gr + hr)));
        float z = 1.f / (1.f + __expf(-(gz + hz)));
        float nn = tanhf(gn + r * hn);
        s_h[t] = (1.f - z) * nn;   // + z*h0 with h0=0
    }
    __syncthreads();
    if (t < 3) {
        float dl = fc_b[t];
        for (int j = 0; j < 32; j++) dl = fmaf(fc_w[t*32 + j], s_h[j], dl);
        out[b*3 + t] = s_om[t] + dl;
    }
}

// ---------------- host ----------------
extern "C" void kernel_launch(void* const* d_in, const int* in_sizes, int n_in,
                              void* d_out, int out_size, void* d_ws, size_t ws_size,
                              hipStream_t stream)
{
    const float* flow = (const float*)d_in[0];
    float* wb = (float*)d_ws;

    // single-pass layout: [wbuf][f2 all 32 batches][f3 all 32 batches] = 196.7 MB
    // (round-3/4 evidence: ws_size >= 275 MB)
    float* f2 = (float*)((char*)d_ws + WBUF_BYTES);
    float* f3 = f2 + (size_t)32 * F2_PB;

    k_cvt<<<1, 256, 0, stream>>>(
        (const float*)d_in[2], (const float*)d_in[5], (const float*)d_in[8], wb);

    // fused stage1+stage2: 300 tiles x 32 batches
    k_fuse12<<<dim3(300, 32), 128, 0, stream>>>(
        flow, (const float*)d_in[1], (const float*)d_in[3],
        (const float*)d_in[4], (const float*)d_in[6], wb, f2);

    k_stage3<<<(32*H3*W3 + 255)/256, 256, 0, stream>>>(
        f2, (const float*)d_in[7], (const float*)d_in[9], wb, f3, 32);

    k_head<<<32, 1024, 0, stream>>>(f3,
        (const float*)d_in[10], (const float*)d_in[11],
        (const float*)d_in[12], (const float*)d_in[13],
        (const float*)d_in[14], (const float*)d_in[15],
        (const float*)d_in[16], (const float*)d_in[18],
        (const float*)d_in[19], (const float*)d_in[20],
        (const float*)d_in[21], (float*)d_out);
}